// Round 14
// baseline (129.980 us; speedup 1.0000x reference)
//
#include <hip/hip_runtime.h>

namespace {
constexpr int PB = 6 * 256;  // 1536 independent (l,n) problems
constexpr int Q = 64;
constexpr int C = 256;
constexpr float EPS_DEN = 1e-7f;
constexpr float EPS_SQRT = 1e-12f;
constexpr int GT_FLOATS = Q * Q;  // 4096 per problem (transposed-packed)
constexpr int AUX_FLOATS = 256;   // xc0[64][2] | x2[64] | c2 partials[8]
constexpr int K1_BLOCKS = 14;     // 10 G-tiles + 4 xc0 strips

__constant__ const int TIARR[10] = {0, 0, 0, 0, 1, 1, 1, 2, 2, 3};
__constant__ const int TJARR[10] = {0, 1, 2, 3, 1, 2, 3, 2, 3, 3};

typedef __attribute__((ext_vector_type(8))) short bf16x8;
typedef __attribute__((ext_vector_type(4))) float f32x4;

// DPP row rotate-add (VALU pipe). Proven R1/R5.
template <int CTRL>
__device__ __forceinline__ float ror_add(float v) {
  int r = __builtin_amdgcn_mov_dpp(__float_as_int(v), CTRL, 0xF, 0xF, true);
  return v + __int_as_float(r);
}

// Canonical GCN wave64 DPP reduction; all-lane result via readlane 63.
// Proven R5-R13 (passed).
__device__ __forceinline__ float wave_total(float v) {
  v = ror_add<0x121>(v);  // row_ror:1
  v = ror_add<0x122>(v);  // row_ror:2
  v = ror_add<0x124>(v);  // row_ror:4
  v = ror_add<0x128>(v);  // row_ror:8
  {
    int t = __builtin_amdgcn_update_dpp(0, __float_as_int(v), 0x142, 0xA, 0xF,
                                        true);  // ROW_BCAST15
    v = v + __int_as_float(t);
  }
  {
    int t = __builtin_amdgcn_update_dpp(0, __float_as_int(v), 0x143, 0xC, 0xF,
                                        true);  // ROW_BCAST31
    v = v + __int_as_float(t);
  }
  return __int_as_float(__builtin_amdgcn_readlane(__float_as_int(v), 63));
}

__device__ __forceinline__ ushort bf16_rne(float x) {
  uint u = __float_as_uint(x);
  return (ushort)((u + 0x7FFFu + ((u >> 16) & 1u)) >> 16);
}
__device__ __forceinline__ float bf16_up(ushort h) {
  return __uint_as_float((uint)h << 16);
}

// fp32 x8 -> bf16 hi/lo planes (identical math since R4).
__device__ __forceinline__ void cvt8(float4 x, float4 y, bf16x8& hh,
                                     bf16x8& ll) {
  float v[8] = {x.x, x.y, x.z, x.w, y.x, y.y, y.z, y.w};
#pragma unroll
  for (int j = 0; j < 8; ++j) {
    ushort h = bf16_rne(v[j]);
    hh[j] = (short)h;
    ll[j] = (short)bf16_rne(v[j] - bf16_up(h));
  }
}

// Compiler-only fence: keeps LDS write->read program order without s_barrier.
// Valid for SINGLE-WAVE blocks: the DS pipe processes a wave's ops in order.
__device__ __forceinline__ void wave_fence() { asm volatile("" ::: "memory"); }
}  // namespace

// -------- kernel 1 (R14): ONE WAVE = ONE 16x16 TILE. grid = PB*14 waves.
// 10 G-tiles (upper triangle, diag reuses A as B) + 4 xc0 strips (strip 0
// also does c2). Tiny register footprint + massive TLP -> fast under ANY
// schedule; immune to the R10-R13 co-compile allocator lottery (VGPR 40-96
// squeezes serialized the staged forms to 56-72 us; healthy was 27).
__global__ __launch_bounds__(64, 4) void k1_gram(const float* __restrict__ hs,
                                                 const float* __restrict__ cen,
                                                 float* __restrict__ ws) {
  const int bid = blockIdx.x;
  const int prob = bid / K1_BLOCKS;
  const int t = bid - prob * K1_BLOCKS;
  const int lane = threadIdx.x;
  const int li = lane & 15, lk = lane >> 4;

  const float* __restrict__ hsb = hs + (size_t)prob * Q * C;
  const float* __restrict__ cenb = cen + (size_t)prob * 2 * C;
  float* gtp = ws + (size_t)prob * GT_FLOATS;
  float* aux = ws + (size_t)PB * GT_FLOATS + (size_t)prob * AUX_FLOATS;

  if (t < 10) {
    // ---- G tile (ti, tj), tj >= ti
    const int ti = TIARR[t], tj = TJARR[t];
    const bool diag = (ti == tj);
    const int rA = 16 * ti + li;
    const int rB = 16 * tj + li;
    f32x4 acc = {0.f, 0.f, 0.f, 0.f};
#pragma unroll
    for (int kk = 0; kk < 8; ++kk) {
      const int kcol = kk * 32 + lk * 8;
      const float* pa = hsb + rA * C + kcol;
      bf16x8 ah, al;
      cvt8(*(const float4*)pa, *(const float4*)(pa + 4), ah, al);
      bf16x8 bh, bl;
      if (diag) {
        bh = ah;
        bl = al;
      } else {
        const float* pb = hsb + rB * C + kcol;
        cvt8(*(const float4*)pb, *(const float4*)(pb + 4), bh, bl);
      }
      acc = __builtin_amdgcn_mfma_f32_16x16x32_bf16(ah, bh, acc, 0, 0, 0);
      acc = __builtin_amdgcn_mfma_f32_16x16x32_bf16(ah, bl, acc, 0, 0, 0);
      acc = __builtin_amdgcn_mfma_f32_16x16x32_bf16(al, bh, acc, 0, 0, 0);
    }
#pragma unroll
    for (int r = 0; r < 4; ++r) {
      const float v = acc[r];
      const int row = 16 * ti + lk * 4 + r;
      const int col = 16 * tj + li;
      gtp[(col >> 2) * 256 + row * 4 + (col & 3)] = v;
      if (!diag) gtp[(row >> 2) * 256 + col * 4 + (row & 3)] = v;
      if (diag && row == col) aux[128 + row] = v;  // x2 = diag(G)
    }
  } else {
    // ---- xc0 strip ti = t-10 (rows 16ti..16ti+15); strip 0 also c2
    const int ti = t - 10;
    const int rA = 16 * ti + li;
    f32x4 accX = {0.f, 0.f, 0.f, 0.f};
#pragma unroll
    for (int kk = 0; kk < 8; ++kk) {
      const int kcol = kk * 32 + lk * 8;
      const float* pa = hsb + rA * C + kcol;
      bf16x8 ah, al;
      cvt8(*(const float4*)pa, *(const float4*)(pa + 4), ah, al);
      bf16x8 cbh = {0, 0, 0, 0, 0, 0, 0, 0};
      bf16x8 cbl = {0, 0, 0, 0, 0, 0, 0, 0};
      if (li < 2) {
        const float* pc = cenb + li * C + kcol;
        cvt8(*(const float4*)pc, *(const float4*)(pc + 4), cbh, cbl);
      }
      accX = __builtin_amdgcn_mfma_f32_16x16x32_bf16(ah, cbh, accX, 0, 0, 0);
      accX = __builtin_amdgcn_mfma_f32_16x16x32_bf16(ah, cbl, accX, 0, 0, 0);
      accX = __builtin_amdgcn_mfma_f32_16x16x32_bf16(al, cbh, accX, 0, 0, 0);
    }
    if (li < 2) {
#pragma unroll
      for (int r = 0; r < 4; ++r) {
        const int q = 16 * ti + lk * 4 + r;
        aux[q * 2 + li] = accX[r];
      }
    }
    if (ti == 0) {
      // c2_0: each lane sums 4 elements per cluster row, then wave reduce
      float s0 = 0.f, s1 = 0.f;
#pragma unroll
      for (int j = 0; j < 4; ++j) {
        float v0 = cenb[lane + 64 * j];
        float v1 = cenb[C + lane + 64 * j];
        s0 = fmaf(v0, v0, s0);
        s1 = fmaf(v1, v1, s1);
      }
      float p0 = wave_total(s0);
      float p1 = wave_total(s1);
      if (lane == 0) {
        aux[192] = p0;
        aux[193] = 0.f;
        aux[194] = 0.f;
        aux[195] = 0.f;
        aux[196] = p1;
        aux[197] = 0.f;
        aux[198] = 0.f;
        aux[199] = 0.f;
      }
    }
  }
}

// -------- kernel 2: 64 EM iterations, 1 wave/problem (R10-proven ~24 us).
// Single bf16 plane for a; direct exp softmax; wave-local fences.
__global__ __launch_bounds__(64, 2) void k2_iter(const float* __restrict__ hs,
                                                 const float* __restrict__ ws,
                                                 float* __restrict__ out) {
  const int prob = blockIdx.x;
  const int lane = threadIdx.x;  // = q
  const int li = lane & 15, lk = lane >> 4;

  __shared__ __align__(16) ushort Ah[2][64];  // a bf16, SoA per cluster
  __shared__ __align__(16) float m_s[2][64];  // m = G.a, SoA per cluster
  __shared__ __align__(16) float a_s[2 * Q];  // final a (epilogue)

  const float4* gt4 = (const float4*)(ws + (size_t)prob * GT_FLOATS);
  const float* aux = ws + (size_t)PB * GT_FLOATS + (size_t)prob * AUX_FLOATS;

  // ---- G -> A-fragments (bf16 split), row = 16t+li, k = kk*32+lk*8+j.
  bf16x8 Gh[4][2], Gl[4][2];
#pragma unroll
  for (int t = 0; t < 4; ++t) {
#pragma unroll
    for (int kk = 0; kk < 2; ++kk) {
      const int cj = 8 * kk + 2 * lk;
      float4 ga = gt4[cj * 64 + 16 * t + li];
      float4 gb = gt4[(cj + 1) * 64 + 16 * t + li];
      float g[8] = {ga.x, ga.y, ga.z, ga.w, gb.x, gb.y, gb.z, gb.w};
      bf16x8 hh, ll;
#pragma unroll
      for (int j = 0; j < 8; ++j) {
        ushort h = bf16_rne(g[j]);
        hh[j] = (short)h;
        ll[j] = (short)bf16_rne(g[j] - bf16_up(h));
      }
      Gh[t][kk] = hh;
      Gl[t][kk] = ll;
    }
  }

  const float x2 = aux[128 + lane];
  float xc0 = aux[lane * 2 + 0];
  float xc1 = aux[lane * 2 + 1];
  float c20 = aux[192] + aux[193] + aux[194] + aux[195];
  float c21 = aux[196] + aux[197] + aux[198] + aux[199];

  float a0 = 0.f, a1 = 0.f;
  const int cl = li & 1;  // cluster this lane's B-frag serves

#pragma unroll 1
  for (int t = 0; t < Q; ++t) {
    float d0 = fmaxf(x2 + c20 - 2.f * xc0, EPS_SQRT);
    float d1 = fmaxf(x2 + c21 - 2.f * xc1, EPS_SQRT);
    float t0 = __builtin_amdgcn_sqrtf(d0), t1 = __builtin_amdgcn_sqrtf(d1);
    // direct softmax: t in [0,~45] so exp(-t) fp32-normal; no max-subtract.
    float e0 = __expf(-t0), e1 = __expf(-t1);
    float inv = __builtin_amdgcn_rcpf(e0 + e1);
    a0 = e0 * inv;
    a1 = e1 * inv;
    if (t == Q - 1) break;

    // ---- a -> bf16 SoA in LDS (2 ds_write_b16)
    Ah[0][lane] = bf16_rne(a0);
    Ah[1][lane] = bf16_rne(a1);
    // den on VALU pipe overlaps the LDS write latency
    float den0 = wave_total(a0);
    float den1 = wave_total(a1);
    wave_fence();  // order: a-writes before B-frag reads (1-wave block)

    // ---- B-fragment of a: col=li (cluster cl), k = kk*32+lk*8+j.
    bf16x8 bh[2];
#pragma unroll
    for (int kk = 0; kk < 2; ++kk)
      bh[kk] = *(const bf16x8*)&Ah[cl][kk * 32 + lk * 8];

    // ---- m = G.a : 16 MFMA, 4 independent chains of 4
    f32x4 acc[4] = {{0.f, 0.f, 0.f, 0.f},
                    {0.f, 0.f, 0.f, 0.f},
                    {0.f, 0.f, 0.f, 0.f},
                    {0.f, 0.f, 0.f, 0.f}};
#pragma unroll
    for (int tt = 0; tt < 4; ++tt) {
#pragma unroll
      for (int kk = 0; kk < 2; ++kk) {
        acc[tt] = __builtin_amdgcn_mfma_f32_16x16x32_bf16(Gh[tt][kk], bh[kk],
                                                          acc[tt], 0, 0, 0);
        acc[tt] = __builtin_amdgcn_mfma_f32_16x16x32_bf16(Gl[tt][kk], bh[kk],
                                                          acc[tt], 0, 0, 0);
      }
    }
    // ---- C-frag (col=li=cluster, row=16t+lk*4+r) -> m_s (4 b128 writes)
    if (li < 2) {
#pragma unroll
      for (int tt = 0; tt < 4; ++tt)
        *(float4*)&m_s[li][16 * tt + lk * 4] =
            make_float4(acc[tt][0], acc[tt][1], acc[tt][2], acc[tt][3]);
    }
    wave_fence();  // order: m-writes before m reads (1-wave block)

    float m0 = m_s[0][lane];
    float m1 = m_s[1][lane];
    float s0 = wave_total(a0 * m0);  // = |num_0|^2
    float s1 = wave_total(a1 * m1);

    float i0 = __builtin_amdgcn_rcpf(den0 + EPS_DEN);
    float i1 = __builtin_amdgcn_rcpf(den1 + EPS_DEN);
    xc0 = m0 * i0;
    xc1 = m1 * i1;
    c20 = s0 * i0 * i0;
    c21 = s1 * i1 * i1;
  }

  // ---- epilogue: centers = (a^T hs)/(den+eps); write assignment
  *(float2*)&a_s[lane * 2] = make_float2(a0, a1);
  float den0 = wave_total(a0);
  float den1 = wave_total(a1);
  wave_fence();
  float i0 = __builtin_amdgcn_rcpf(den0 + EPS_DEN);
  float i1 = __builtin_amdgcn_rcpf(den1 + EPS_DEN);

  const float4* hb4 = (const float4*)(hs + (size_t)prob * Q * C);
  const float2* a2 = (const float2*)a_s;
  float4 n0 = make_float4(0.f, 0.f, 0.f, 0.f);
  float4 n1 = make_float4(0.f, 0.f, 0.f, 0.f);
#pragma unroll 8
  for (int q2 = 0; q2 < Q; ++q2) {
    float4 h = hb4[q2 * 64 + lane];
    float2 aq = a2[q2];
    n0.x = fmaf(aq.x, h.x, n0.x);
    n0.y = fmaf(aq.x, h.y, n0.y);
    n0.z = fmaf(aq.x, h.z, n0.z);
    n0.w = fmaf(aq.x, h.w, n0.w);
    n1.x = fmaf(aq.y, h.x, n1.x);
    n1.y = fmaf(aq.y, h.y, n1.y);
    n1.z = fmaf(aq.y, h.z, n1.z);
    n1.w = fmaf(aq.y, h.w, n1.w);
  }
  float4* outc4 = (float4*)(out + (size_t)prob * 2 * C);
  outc4[lane] = make_float4(n0.x * i0, n0.y * i0, n0.z * i0, n0.w * i0);
  outc4[64 + lane] = make_float4(n1.x * i1, n1.y * i1, n1.z * i1, n1.w * i1);

  float* outa = out + (size_t)PB * 2 * C + (size_t)prob * Q * 2;
  *(float2*)&outa[lane * 2] = make_float2(a0, a1);
}

extern "C" void kernel_launch(void* const* d_in, const int* in_sizes, int n_in,
                              void* d_out, int out_size, void* d_ws,
                              size_t ws_size, hipStream_t stream) {
  const float* hs = (const float*)d_in[0];
  const float* cen = (const float*)d_in[1];
  float* out = (float*)d_out;
  float* ws = (float*)d_ws;  // needs PB*(4096+256)*4 B ~= 26.8 MB
  hipLaunchKernelGGL(k1_gram, dim3(PB * K1_BLOCKS), dim3(64), 0, stream, hs,
                     cen, ws);
  hipLaunchKernelGGL(k2_iter, dim3(PB), dim3(64), 0, stream, hs, ws, out);
}

// Round 15
// 87.812 us; speedup vs baseline: 1.4802x; 1.4802x over previous
//
#include <hip/hip_runtime.h>

namespace {
constexpr int PB = 6 * 256;  // 1536 independent (l,n) problems
constexpr int Q = 64;
constexpr int C = 256;
constexpr float EPS_DEN = 1e-7f;
constexpr float EPS_SQRT = 1e-12f;
constexpr int GT_FLOATS = Q * Q;  // 4096 per problem (transposed-packed)
constexpr int AUX_FLOATS = 256;   // xc0[64][2] | x2[64] | c2 partials[8]

typedef __attribute__((ext_vector_type(8))) short bf16x8;
typedef __attribute__((ext_vector_type(4))) float f32x4;

// DPP row rotate-add (VALU pipe). Proven R1/R5.
template <int CTRL>
__device__ __forceinline__ float ror_add(float v) {
  int r = __builtin_amdgcn_mov_dpp(__float_as_int(v), CTRL, 0xF, 0xF, true);
  return v + __int_as_float(r);
}

// Canonical GCN wave64 DPP reduction; all-lane result via readlane 63.
// Proven R5-R14 (passed).
__device__ __forceinline__ float wave_total(float v) {
  v = ror_add<0x121>(v);  // row_ror:1
  v = ror_add<0x122>(v);  // row_ror:2
  v = ror_add<0x124>(v);  // row_ror:4
  v = ror_add<0x128>(v);  // row_ror:8
  {
    int t = __builtin_amdgcn_update_dpp(0, __float_as_int(v), 0x142, 0xA, 0xF,
                                        true);  // ROW_BCAST15
    v = v + __int_as_float(t);
  }
  {
    int t = __builtin_amdgcn_update_dpp(0, __float_as_int(v), 0x143, 0xC, 0xF,
                                        true);  // ROW_BCAST31
    v = v + __int_as_float(t);
  }
  return __int_as_float(__builtin_amdgcn_readlane(__float_as_int(v), 63));
}

__device__ __forceinline__ ushort bf16_rne(float x) {
  uint u = __float_as_uint(x);
  return (ushort)((u + 0x7FFFu + ((u >> 16) & 1u)) >> 16);
}
__device__ __forceinline__ float bf16_up(ushort h) {
  return __uint_as_float((uint)h << 16);
}

// fp32 x8 -> bf16 hi/lo planes (identical math since R4).
__device__ __forceinline__ void cvt8(float4 x, float4 y, bf16x8& hh,
                                     bf16x8& ll) {
  float v[8] = {x.x, x.y, x.z, x.w, y.x, y.y, y.z, y.w};
#pragma unroll
  for (int j = 0; j < 8; ++j) {
    ushort h = bf16_rne(v[j]);
    hh[j] = (short)h;
    ll[j] = (short)bf16_rne(v[j] - bf16_up(h));
  }
}

// async global->LDS, 16B per lane, no VGPR round-trip.
__device__ __forceinline__ void gload_lds16(const float* src, float* lds_dst) {
  __builtin_amdgcn_global_load_lds(
      (const __attribute__((address_space(1))) unsigned int*)src,
      (__attribute__((address_space(3))) unsigned int*)lds_dst, 16, 0, 0);
}

// Compiler-only fence: keeps LDS write->read program order without s_barrier.
// Valid for SINGLE-WAVE blocks: the DS pipe processes a wave's ops in order.
__device__ __forceinline__ void wave_fence() { asm volatile("" ::: "memory"); }
}  // namespace

// -------- kernel 1 (R15): DMA-staged quarters. global_load_lds stages hs
// with ZERO staging VGPRs (allocator-squeeze-proof; R10-R14 lottery: plain
// staged loads serialized at VGPR 40-96, 27->57-81 us). Per quarter (64 cols):
// each wave DMAs its 16 rows with pre-swizzled global source (16B granule
// hg ^= (r&7)<<1) -> linear LDS; barrier drains vmcnt; R9 MFMA scheme reads
// fp32 from LDS, cvt8 on the fly (~50 live VGPRs). hs read from HBM ONCE.
__global__ __launch_bounds__(256, 2) void k1_gram(
    const float* __restrict__ hs, const float* __restrict__ cen,
    float* __restrict__ ws) {
  const int prob = blockIdx.x;
  const int tid = threadIdx.x;
  const int lane = tid & 63, w = tid >> 6;
  const int li = lane & 15, lk = lane >> 4;

  __shared__ __align__(16) float Fq[64 * 64];  // one 64-col quarter, swizzled

  const float* __restrict__ hsb = hs + (size_t)prob * Q * C;
  const float* __restrict__ cenb = cen + (size_t)prob * 2 * C;
  float* gtp = ws + (size_t)prob * GT_FLOATS;
  float* aux = ws + (size_t)PB * GT_FLOATS + (size_t)prob * AUX_FLOATS;

  // ---- c2_0 partials (fp32 exact; identical to R9)
  {
    float c0v = cenb[tid];
    float c1v = cenb[C + tid];
    float p0 = wave_total(c0v * c0v);
    float p1 = wave_total(c1v * c1v);
    if (lane == 0) {
      aux[192 + w] = p0;
      aux[196 + w] = p1;
    }
  }

  f32x4 acc[4] = {{0.f, 0.f, 0.f, 0.f},
                  {0.f, 0.f, 0.f, 0.f},
                  {0.f, 0.f, 0.f, 0.f},
                  {0.f, 0.f, 0.f, 0.f}};
  f32x4 accX = {0.f, 0.f, 0.f, 0.f};
  const int rA = 16 * w + li;

#pragma unroll 1
  for (int q = 0; q < 4; ++q) {
    // ---- DMA this wave's 16 rows (4 x 1KB calls). LDS dest is wave-uniform
    // base + lane*16 (HW rule); global src carries the swizzle.
#pragma unroll
    for (int i = 0; i < 4; ++i) {
      const int j = w * 4 + i;             // 1KB chunk = 4 rows
      const int r = 4 * j + (lane >> 4);   // row this lane feeds
      const int hg = lane & 15;            // 16B half-granule within row
      const float* src =
          hsb + r * C + q * 64 + ((hg ^ ((r & 7) << 1)) << 2);
      gload_lds16(src, Fq + j * 256);      // wave-uniform LDS base
    }
    __syncthreads();  // compiler drains vmcnt before barrier: staging done

#pragma unroll
    for (int kk2 = 0; kk2 < 2; ++kk2) {
      const int kk = q * 2 + kk2;
      const int hg0 = kk2 * 8 + lk * 2;
      // A-fragment from LDS (swizzled), cvt on the fly
      bf16x8 ah, al;
      {
        float4 f0 = *(const float4*)&Fq[rA * 64 + ((hg0 ^ ((rA & 7) << 1)) << 2)];
        float4 f1 =
            *(const float4*)&Fq[rA * 64 + (((hg0 + 1) ^ ((rA & 7) << 1)) << 2)];
        cvt8(f0, f1, ah, al);
      }
      // xc0 B-fragment straight from global cen (2 rows, L2-resident)
      bf16x8 cbh = {0, 0, 0, 0, 0, 0, 0, 0};
      bf16x8 cbl = {0, 0, 0, 0, 0, 0, 0, 0};
      if (li < 2) {
        const float* pc = cenb + li * C + kk * 32 + lk * 8;
        cvt8(*(const float4*)pc, *(const float4*)(pc + 4), cbh, cbl);
      }
      accX = __builtin_amdgcn_mfma_f32_16x16x32_bf16(ah, cbh, accX, 0, 0, 0);
      accX = __builtin_amdgcn_mfma_f32_16x16x32_bf16(ah, cbl, accX, 0, 0, 0);
      accX = __builtin_amdgcn_mfma_f32_16x16x32_bf16(al, cbh, accX, 0, 0, 0);

#pragma unroll
      for (int tj = 0; tj < 4; ++tj) {
        if (tj < w) continue;  // wave-uniform skip (symmetry)
        const int rB = 16 * tj + li;
        float4 g0 =
            *(const float4*)&Fq[rB * 64 + ((hg0 ^ ((rB & 7) << 1)) << 2)];
        float4 g1 =
            *(const float4*)&Fq[rB * 64 + (((hg0 + 1) ^ ((rB & 7) << 1)) << 2)];
        bf16x8 bh, bl;
        cvt8(g0, g1, bh, bl);
        acc[tj] =
            __builtin_amdgcn_mfma_f32_16x16x32_bf16(ah, bh, acc[tj], 0, 0, 0);
        acc[tj] =
            __builtin_amdgcn_mfma_f32_16x16x32_bf16(ah, bl, acc[tj], 0, 0, 0);
        acc[tj] =
            __builtin_amdgcn_mfma_f32_16x16x32_bf16(al, bh, acc[tj], 0, 0, 0);
      }
    }
    __syncthreads();  // all reads done before next quarter's DMA overwrites
  }

  // ---- epilogue: scatter G (and mirror), diag -> x2, xc0 (same as R9)
#pragma unroll
  for (int tj = 0; tj < 4; ++tj) {
    if (tj < w) continue;
#pragma unroll
    for (int r = 0; r < 4; ++r) {
      const float v = acc[tj][r];
      const int row = 16 * w + lk * 4 + r;
      const int col = 16 * tj + li;
      gtp[(col >> 2) * 256 + row * 4 + (col & 3)] = v;
      if (tj > w) gtp[(row >> 2) * 256 + col * 4 + (row & 3)] = v;
      if (row == col) aux[128 + row] = v;
    }
  }
  if (li < 2) {
#pragma unroll
    for (int r = 0; r < 4; ++r) {
      const int q = 16 * w + lk * 4 + r;
      aux[q * 2 + li] = accX[r];
    }
  }
}

// -------- kernel 2: 64 EM iterations, 1 wave/problem (R10-proven ~24 us).
// Single bf16 plane for a; direct exp softmax; wave-local fences.
__global__ __launch_bounds__(64, 2) void k2_iter(const float* __restrict__ hs,
                                                 const float* __restrict__ ws,
                                                 float* __restrict__ out) {
  const int prob = blockIdx.x;
  const int lane = threadIdx.x;  // = q
  const int li = lane & 15, lk = lane >> 4;

  __shared__ __align__(16) ushort Ah[2][64];  // a bf16, SoA per cluster
  __shared__ __align__(16) float m_s[2][64];  // m = G.a, SoA per cluster
  __shared__ __align__(16) float a_s[2 * Q];  // final a (epilogue)

  const float4* gt4 = (const float4*)(ws + (size_t)prob * GT_FLOATS);
  const float* aux = ws + (size_t)PB * GT_FLOATS + (size_t)prob * AUX_FLOATS;

  // ---- G -> A-fragments (bf16 split), row = 16t+li, k = kk*32+lk*8+j.
  bf16x8 Gh[4][2], Gl[4][2];
#pragma unroll
  for (int t = 0; t < 4; ++t) {
#pragma unroll
    for (int kk = 0; kk < 2; ++kk) {
      const int cj = 8 * kk + 2 * lk;
      float4 ga = gt4[cj * 64 + 16 * t + li];
      float4 gb = gt4[(cj + 1) * 64 + 16 * t + li];
      float g[8] = {ga.x, ga.y, ga.z, ga.w, gb.x, gb.y, gb.z, gb.w};
      bf16x8 hh, ll;
#pragma unroll
      for (int j = 0; j < 8; ++j) {
        ushort h = bf16_rne(g[j]);
        hh[j] = (short)h;
        ll[j] = (short)bf16_rne(g[j] - bf16_up(h));
      }
      Gh[t][kk] = hh;
      Gl[t][kk] = ll;
    }
  }

  const float x2 = aux[128 + lane];
  float xc0 = aux[lane * 2 + 0];
  float xc1 = aux[lane * 2 + 1];
  float c20 = aux[192] + aux[193] + aux[194] + aux[195];
  float c21 = aux[196] + aux[197] + aux[198] + aux[199];

  float a0 = 0.f, a1 = 0.f;
  const int cl = li & 1;  // cluster this lane's B-frag serves

#pragma unroll 1
  for (int t = 0; t < Q; ++t) {
    float d0 = fmaxf(x2 + c20 - 2.f * xc0, EPS_SQRT);
    float d1 = fmaxf(x2 + c21 - 2.f * xc1, EPS_SQRT);
    float t0 = __builtin_amdgcn_sqrtf(d0), t1 = __builtin_amdgcn_sqrtf(d1);
    // direct softmax: t in [0,~45] so exp(-t) fp32-normal; no max-subtract.
    float e0 = __expf(-t0), e1 = __expf(-t1);
    float inv = __builtin_amdgcn_rcpf(e0 + e1);
    a0 = e0 * inv;
    a1 = e1 * inv;
    if (t == Q - 1) break;

    // ---- a -> bf16 SoA in LDS (2 ds_write_b16)
    Ah[0][lane] = bf16_rne(a0);
    Ah[1][lane] = bf16_rne(a1);
    // den on VALU pipe overlaps the LDS write latency
    float den0 = wave_total(a0);
    float den1 = wave_total(a1);
    wave_fence();  // order: a-writes before B-frag reads (1-wave block)

    // ---- B-fragment of a: col=li (cluster cl), k = kk*32+lk*8+j.
    bf16x8 bh[2];
#pragma unroll
    for (int kk = 0; kk < 2; ++kk)
      bh[kk] = *(const bf16x8*)&Ah[cl][kk * 32 + lk * 8];

    // ---- m = G.a : 16 MFMA, 4 independent chains of 4
    f32x4 acc[4] = {{0.f, 0.f, 0.f, 0.f},
                    {0.f, 0.f, 0.f, 0.f},
                    {0.f, 0.f, 0.f, 0.f},
                    {0.f, 0.f, 0.f, 0.f}};
#pragma unroll
    for (int tt = 0; tt < 4; ++tt) {
#pragma unroll
      for (int kk = 0; kk < 2; ++kk) {
        acc[tt] = __builtin_amdgcn_mfma_f32_16x16x32_bf16(Gh[tt][kk], bh[kk],
                                                          acc[tt], 0, 0, 0);
        acc[tt] = __builtin_amdgcn_mfma_f32_16x16x32_bf16(Gl[tt][kk], bh[kk],
                                                          acc[tt], 0, 0, 0);
      }
    }
    // ---- C-frag (col=li=cluster, row=16t+lk*4+r) -> m_s (4 b128 writes)
    if (li < 2) {
#pragma unroll
      for (int tt = 0; tt < 4; ++tt)
        *(float4*)&m_s[li][16 * tt + lk * 4] =
            make_float4(acc[tt][0], acc[tt][1], acc[tt][2], acc[tt][3]);
    }
    wave_fence();  // order: m-writes before m reads (1-wave block)

    float m0 = m_s[0][lane];
    float m1 = m_s[1][lane];
    float s0 = wave_total(a0 * m0);  // = |num_0|^2
    float s1 = wave_total(a1 * m1);

    float i0 = __builtin_amdgcn_rcpf(den0 + EPS_DEN);
    float i1 = __builtin_amdgcn_rcpf(den1 + EPS_DEN);
    xc0 = m0 * i0;
    xc1 = m1 * i1;
    c20 = s0 * i0 * i0;
    c21 = s1 * i1 * i1;
  }

  // ---- epilogue: centers = (a^T hs)/(den+eps); write assignment
  *(float2*)&a_s[lane * 2] = make_float2(a0, a1);
  float den0 = wave_total(a0);
  float den1 = wave_total(a1);
  wave_fence();
  float i0 = __builtin_amdgcn_rcpf(den0 + EPS_DEN);
  float i1 = __builtin_amdgcn_rcpf(den1 + EPS_DEN);

  const float4* hb4 = (const float4*)(hs + (size_t)prob * Q * C);
  const float2* a2 = (const float2*)a_s;
  float4 n0 = make_float4(0.f, 0.f, 0.f, 0.f);
  float4 n1 = make_float4(0.f, 0.f, 0.f, 0.f);
#pragma unroll 8
  for (int q2 = 0; q2 < Q; ++q2) {
    float4 h = hb4[q2 * 64 + lane];
    float2 aq = a2[q2];
    n0.x = fmaf(aq.x, h.x, n0.x);
    n0.y = fmaf(aq.x, h.y, n0.y);
    n0.z = fmaf(aq.x, h.z, n0.z);
    n0.w = fmaf(aq.x, h.w, n0.w);
    n1.x = fmaf(aq.y, h.x, n1.x);
    n1.y = fmaf(aq.y, h.y, n1.y);
    n1.z = fmaf(aq.y, h.z, n1.z);
    n1.w = fmaf(aq.y, h.w, n1.w);
  }
  float4* outc4 = (float4*)(out + (size_t)prob * 2 * C);
  outc4[lane] = make_float4(n0.x * i0, n0.y * i0, n0.z * i0, n0.w * i0);
  outc4[64 + lane] = make_float4(n1.x * i1, n1.y * i1, n1.z * i1, n1.w * i1);

  float* outa = out + (size_t)PB * 2 * C + (size_t)prob * Q * 2;
  *(float2*)&outa[lane * 2] = make_float2(a0, a1);
}

extern "C" void kernel_launch(void* const* d_in, const int* in_sizes, int n_in,
                              void* d_out, int out_size, void* d_ws,
                              size_t ws_size, hipStream_t stream) {
  const float* hs = (const float*)d_in[0];
  const float* cen = (const float*)d_in[1];
  float* out = (float*)d_out;
  float* ws = (float*)d_ws;  // needs PB*(4096+256)*4 B ~= 26.8 MB
  hipLaunchKernelGGL(k1_gram, dim3(PB), dim3(256), 0, stream, hs, cen, ws);
  hipLaunchKernelGGL(k2_iter, dim3(PB), dim3(64), 0, stream, hs, ws, out);
}

// Round 16
// 85.388 us; speedup vs baseline: 1.5222x; 1.0284x over previous
//
#include <hip/hip_runtime.h>

namespace {
constexpr int PB = 6 * 256;  // 1536 independent (l,n) problems
constexpr int Q = 64;
constexpr int C = 256;
constexpr float EPS_DEN = 1e-7f;
constexpr float EPS_SQRT = 1e-12f;

typedef __attribute__((ext_vector_type(8))) short bf16x8;
typedef __attribute__((ext_vector_type(4))) float f32x4;

// DPP row rotate-add (VALU pipe). Proven R1/R5.
template <int CTRL>
__device__ __forceinline__ float ror_add(float v) {
  int r = __builtin_amdgcn_mov_dpp(__float_as_int(v), CTRL, 0xF, 0xF, true);
  return v + __int_as_float(r);
}

// Canonical GCN wave64 DPP reduction; all-lane result via readlane 63.
// Proven R5-R15 (passed).
__device__ __forceinline__ float wave_total(float v) {
  v = ror_add<0x121>(v);  // row_ror:1
  v = ror_add<0x122>(v);  // row_ror:2
  v = ror_add<0x124>(v);  // row_ror:4
  v = ror_add<0x128>(v);  // row_ror:8
  {
    int t = __builtin_amdgcn_update_dpp(0, __float_as_int(v), 0x142, 0xA, 0xF,
                                        true);  // ROW_BCAST15
    v = v + __int_as_float(t);
  }
  {
    int t = __builtin_amdgcn_update_dpp(0, __float_as_int(v), 0x143, 0xC, 0xF,
                                        true);  // ROW_BCAST31
    v = v + __int_as_float(t);
  }
  return __int_as_float(__builtin_amdgcn_readlane(__float_as_int(v), 63));
}

__device__ __forceinline__ ushort bf16_rne(float x) {
  uint u = __float_as_uint(x);
  return (ushort)((u + 0x7FFFu + ((u >> 16) & 1u)) >> 16);
}
__device__ __forceinline__ float bf16_up(ushort h) {
  return __uint_as_float((uint)h << 16);
}

// fp32 x8 -> bf16 hi/lo planes (identical math since R4).
__device__ __forceinline__ void cvt8(float4 x, float4 y, bf16x8& hh,
                                     bf16x8& ll) {
  float v[8] = {x.x, x.y, x.z, x.w, y.x, y.y, y.z, y.w};
#pragma unroll
  for (int j = 0; j < 8; ++j) {
    ushort h = bf16_rne(v[j]);
    hh[j] = (short)h;
    ll[j] = (short)bf16_rne(v[j] - bf16_up(h));
  }
}

// async global->LDS, 16B per lane, no VGPR round-trip (R15-proven).
__device__ __forceinline__ void gload_lds16(const float* src, float* lds_dst) {
  __builtin_amdgcn_global_load_lds(
      (const __attribute__((address_space(1))) unsigned int*)src,
      (__attribute__((address_space(3))) unsigned int*)lds_dst, 16, 0, 0);
}

// Compiler-only fence: keeps LDS write->read program order without s_barrier.
// Valid for SINGLE-WAVE sections (DS pipe is in-order per wave). R9-proven.
__device__ __forceinline__ void wave_fence() { asm volatile("" ::: "memory"); }
}  // namespace

// -------- FUSED kernel (R16): one block = one problem, end to end.
// Phase 1 (4 waves) = R15's k1 verbatim, but G + aux land in LDS (no HBM
// round-trip). Waves 1-3 then RETURN (VGPRs free -> more blocks resident);
// wave 0 runs R10's k2 loop from LDS. Cross-block phase overlap replaces the
// chip-wide k1->k2 serialization that left each kernel stall-bound.
__global__ __launch_bounds__(256, 2) void em_fused(
    const float* __restrict__ hs, const float* __restrict__ cen,
    float* __restrict__ out) {
  const int prob = blockIdx.x;
  const int tid = threadIdx.x;
  const int lane = tid & 63, w = tid >> 6;
  const int li = lane & 15, lk = lane >> 4;

  __shared__ __align__(16) float Gs[64 * 64];  // quarter buffer, then G
  __shared__ __align__(16) float aux_s[256];   // xc0[128] | x2[64] | c2[8]
  __shared__ __align__(16) ushort Ahs[2][64];  // phase-2: a bf16 SoA
  __shared__ __align__(16) float m_s[2][64];   // phase-2: m = G.a
  __shared__ __align__(16) float a_s[2 * Q];   // phase-2: final a

  const float* __restrict__ hsb = hs + (size_t)prob * Q * C;
  const float* __restrict__ cenb = cen + (size_t)prob * 2 * C;

  // ======== PHASE 1: G = H H^T, xc0, x2, c2 (R15 k1 body) ========
  {
    float c0v = cenb[tid];
    float c1v = cenb[C + tid];
    float p0 = wave_total(c0v * c0v);
    float p1 = wave_total(c1v * c1v);
    if (lane == 0) {
      aux_s[192 + w] = p0;
      aux_s[196 + w] = p1;
    }
  }

  f32x4 acc[4] = {{0.f, 0.f, 0.f, 0.f},
                  {0.f, 0.f, 0.f, 0.f},
                  {0.f, 0.f, 0.f, 0.f},
                  {0.f, 0.f, 0.f, 0.f}};
  f32x4 accX = {0.f, 0.f, 0.f, 0.f};
  const int rA = 16 * w + li;

#pragma unroll 1
  for (int q = 0; q < 4; ++q) {
    // DMA this wave's 16 rows (4 x 1KB). LDS dest wave-uniform + lane*16;
    // global source carries the 16B-granule swizzle hg ^= (r&7)<<1.
#pragma unroll
    for (int i = 0; i < 4; ++i) {
      const int j = w * 4 + i;
      const int r = 4 * j + (lane >> 4);
      const int hg = lane & 15;
      const float* src = hsb + r * C + q * 64 + ((hg ^ ((r & 7) << 1)) << 2);
      gload_lds16(src, Gs + j * 256);
    }
    __syncthreads();  // drain vmcnt: staging visible

#pragma unroll
    for (int kk2 = 0; kk2 < 2; ++kk2) {
      const int kk = q * 2 + kk2;
      const int hg0 = kk2 * 8 + lk * 2;
      bf16x8 ah, al;
      {
        float4 f0 =
            *(const float4*)&Gs[rA * 64 + ((hg0 ^ ((rA & 7) << 1)) << 2)];
        float4 f1 =
            *(const float4*)&Gs[rA * 64 + (((hg0 + 1) ^ ((rA & 7) << 1)) << 2)];
        cvt8(f0, f1, ah, al);
      }
      bf16x8 cbh = {0, 0, 0, 0, 0, 0, 0, 0};
      bf16x8 cbl = {0, 0, 0, 0, 0, 0, 0, 0};
      if (li < 2) {
        const float* pc = cenb + li * C + kk * 32 + lk * 8;
        cvt8(*(const float4*)pc, *(const float4*)(pc + 4), cbh, cbl);
      }
      accX = __builtin_amdgcn_mfma_f32_16x16x32_bf16(ah, cbh, accX, 0, 0, 0);
      accX = __builtin_amdgcn_mfma_f32_16x16x32_bf16(ah, cbl, accX, 0, 0, 0);
      accX = __builtin_amdgcn_mfma_f32_16x16x32_bf16(al, cbh, accX, 0, 0, 0);

#pragma unroll
      for (int tj = 0; tj < 4; ++tj) {
        if (tj < w) continue;  // wave-uniform skip (symmetry)
        const int rB = 16 * tj + li;
        float4 g0 =
            *(const float4*)&Gs[rB * 64 + ((hg0 ^ ((rB & 7) << 1)) << 2)];
        float4 g1 =
            *(const float4*)&Gs[rB * 64 + (((hg0 + 1) ^ ((rB & 7) << 1)) << 2)];
        bf16x8 bh, bl;
        cvt8(g0, g1, bh, bl);
        acc[tj] =
            __builtin_amdgcn_mfma_f32_16x16x32_bf16(ah, bh, acc[tj], 0, 0, 0);
        acc[tj] =
            __builtin_amdgcn_mfma_f32_16x16x32_bf16(ah, bl, acc[tj], 0, 0, 0);
        acc[tj] =
            __builtin_amdgcn_mfma_f32_16x16x32_bf16(al, bh, acc[tj], 0, 0, 0);
      }
    }
    __syncthreads();  // all reads done before next quarter / G overwrite
  }

  // ---- G epilogue -> LDS (same layout as old ws gtp; Gs reused)
#pragma unroll
  for (int tj = 0; tj < 4; ++tj) {
    if (tj < w) continue;
#pragma unroll
    for (int r = 0; r < 4; ++r) {
      const float v = acc[tj][r];
      const int row = 16 * w + lk * 4 + r;
      const int col = 16 * tj + li;
      Gs[(col >> 2) * 256 + row * 4 + (col & 3)] = v;
      if (tj > w) Gs[(row >> 2) * 256 + col * 4 + (row & 3)] = v;
      if (row == col) aux_s[128 + row] = v;
    }
  }
  if (li < 2) {
#pragma unroll
    for (int r = 0; r < 4; ++r) {
      const int qq = 16 * w + lk * 4 + r;
      aux_s[qq * 2 + li] = accX[r];
    }
  }
  __syncthreads();  // publish G + aux to wave 0

  // ======== PHASE 2: 64 EM iterations, wave 0 only (R10 k2 body) ========
  if (w != 0) return;  // free waves 1-3 (VGPRs release -> deeper pipelining)

  const float4* gt4 = (const float4*)Gs;

  bf16x8 Gh[4][2], Gl[4][2];
#pragma unroll
  for (int t = 0; t < 4; ++t) {
#pragma unroll
    for (int kk = 0; kk < 2; ++kk) {
      const int cj = 8 * kk + 2 * lk;
      float4 ga = gt4[cj * 64 + 16 * t + li];
      float4 gb = gt4[(cj + 1) * 64 + 16 * t + li];
      float g[8] = {ga.x, ga.y, ga.z, ga.w, gb.x, gb.y, gb.z, gb.w};
      bf16x8 hh, ll;
#pragma unroll
      for (int j = 0; j < 8; ++j) {
        ushort h = bf16_rne(g[j]);
        hh[j] = (short)h;
        ll[j] = (short)bf16_rne(g[j] - bf16_up(h));
      }
      Gh[t][kk] = hh;
      Gl[t][kk] = ll;
    }
  }

  const float x2 = aux_s[128 + lane];
  float xc0 = aux_s[lane * 2 + 0];
  float xc1 = aux_s[lane * 2 + 1];
  float c20 = aux_s[192] + aux_s[193] + aux_s[194] + aux_s[195];
  float c21 = aux_s[196] + aux_s[197] + aux_s[198] + aux_s[199];

  float a0 = 0.f, a1 = 0.f;
  const int cl = li & 1;  // cluster this lane's B-frag serves

#pragma unroll 1
  for (int t = 0; t < Q; ++t) {
    float d0 = fmaxf(x2 + c20 - 2.f * xc0, EPS_SQRT);
    float d1 = fmaxf(x2 + c21 - 2.f * xc1, EPS_SQRT);
    float t0 = __builtin_amdgcn_sqrtf(d0), t1 = __builtin_amdgcn_sqrtf(d1);
    // direct softmax: t in [0,~45] so exp(-t) fp32-normal; no max-subtract.
    float e0 = __expf(-t0), e1 = __expf(-t1);
    float inv = __builtin_amdgcn_rcpf(e0 + e1);
    a0 = e0 * inv;
    a1 = e1 * inv;
    if (t == Q - 1) break;

    // a -> bf16 SoA in LDS (2 ds_write_b16)
    Ahs[0][lane] = bf16_rne(a0);
    Ahs[1][lane] = bf16_rne(a1);
    // den on VALU pipe overlaps the LDS write latency
    float den0 = wave_total(a0);
    float den1 = wave_total(a1);
    wave_fence();  // order: a-writes before B-frag reads (1 wave)

    bf16x8 bh[2];
#pragma unroll
    for (int kk = 0; kk < 2; ++kk)
      bh[kk] = *(const bf16x8*)&Ahs[cl][kk * 32 + lk * 8];

    // m = G.a : 16 MFMA, 4 independent chains of 4
    f32x4 macc[4] = {{0.f, 0.f, 0.f, 0.f},
                     {0.f, 0.f, 0.f, 0.f},
                     {0.f, 0.f, 0.f, 0.f},
                     {0.f, 0.f, 0.f, 0.f}};
#pragma unroll
    for (int tt = 0; tt < 4; ++tt) {
#pragma unroll
      for (int kk = 0; kk < 2; ++kk) {
        macc[tt] = __builtin_amdgcn_mfma_f32_16x16x32_bf16(Gh[tt][kk], bh[kk],
                                                           macc[tt], 0, 0, 0);
        macc[tt] = __builtin_amdgcn_mfma_f32_16x16x32_bf16(Gl[tt][kk], bh[kk],
                                                           macc[tt], 0, 0, 0);
      }
    }
    if (li < 2) {
#pragma unroll
      for (int tt = 0; tt < 4; ++tt)
        *(float4*)&m_s[li][16 * tt + lk * 4] = make_float4(
            macc[tt][0], macc[tt][1], macc[tt][2], macc[tt][3]);
    }
    wave_fence();  // order: m-writes before m reads (1 wave)

    float m0 = m_s[0][lane];
    float m1 = m_s[1][lane];
    float s0 = wave_total(a0 * m0);  // = |num_0|^2
    float s1 = wave_total(a1 * m1);

    float i0 = __builtin_amdgcn_rcpf(den0 + EPS_DEN);
    float i1 = __builtin_amdgcn_rcpf(den1 + EPS_DEN);
    xc0 = m0 * i0;
    xc1 = m1 * i1;
    c20 = s0 * i0 * i0;
    c21 = s1 * i1 * i1;
  }

  // ---- epilogue: centers = (a^T hs)/(den+eps); write assignment
  *(float2*)&a_s[lane * 2] = make_float2(a0, a1);
  float den0 = wave_total(a0);
  float den1 = wave_total(a1);
  wave_fence();
  float i0 = __builtin_amdgcn_rcpf(den0 + EPS_DEN);
  float i1 = __builtin_amdgcn_rcpf(den1 + EPS_DEN);

  const float4* hb4 = (const float4*)hsb;
  const float2* a2 = (const float2*)a_s;
  float4 n0 = make_float4(0.f, 0.f, 0.f, 0.f);
  float4 n1 = make_float4(0.f, 0.f, 0.f, 0.f);
#pragma unroll 8
  for (int q2 = 0; q2 < Q; ++q2) {
    float4 h = hb4[q2 * 64 + lane];
    float2 aq = a2[q2];
    n0.x = fmaf(aq.x, h.x, n0.x);
    n0.y = fmaf(aq.x, h.y, n0.y);
    n0.z = fmaf(aq.x, h.z, n0.z);
    n0.w = fmaf(aq.x, h.w, n0.w);
    n1.x = fmaf(aq.y, h.x, n1.x);
    n1.y = fmaf(aq.y, h.y, n1.y);
    n1.z = fmaf(aq.y, h.z, n1.z);
    n1.w = fmaf(aq.y, h.w, n1.w);
  }
  float4* outc4 = (float4*)(out + (size_t)prob * 2 * C);
  outc4[lane] = make_float4(n0.x * i0, n0.y * i0, n0.z * i0, n0.w * i0);
  outc4[64 + lane] = make_float4(n1.x * i1, n1.y * i1, n1.z * i1, n1.w * i1);

  float* outa = out + (size_t)PB * 2 * C + (size_t)prob * Q * 2;
  *(float2*)&outa[lane * 2] = make_float2(a0, a1);
}

extern "C" void kernel_launch(void* const* d_in, const int* in_sizes, int n_in,
                              void* d_out, int out_size, void* d_ws,
                              size_t ws_size, hipStream_t stream) {
  const float* hs = (const float*)d_in[0];
  const float* cen = (const float*)d_in[1];
  float* out = (float*)d_out;
  hipLaunchKernelGGL(em_fused, dim3(PB), dim3(256), 0, stream, hs, cen, out);
}